// Round 10
// baseline (71.669 us; speedup 1.0000x reference)
//
#include <hip/hip_runtime.h>
#include <hip/hip_bf16.h>
#include <math.h>

namespace {

typedef float f32x4 __attribute__((ext_vector_type(4)));
typedef float f32x16 __attribute__((ext_vector_type(16)));
typedef short bf16x8 __attribute__((ext_vector_type(8)));

constexpr int Bc = 32, Nc = 8192, Dc = 128, Kc = 64;
constexpr int PB = 32;            // blocks per batch (grid = 1024)
constexpr int RPB = Nc / PB;      // 256 rows per block
constexpr int NT = 64;            // rows per iteration tile
constexpr int ITERS = RPB / NT;   // 4
constexpr int XSTR = 136;         // xS row stride in shorts (272 B, 16B-aligned)

// packed bf16 pair via v_cvt_pk_bf16_f32 (compiler-emitted, RNE)
__device__ __forceinline__ unsigned int pk(float a, float b) {
  union { __hip_bfloat162 h; unsigned int u; } c;
  c.h = __float22bfloat162_rn(make_float2(a, b));
  return c.u;
}
__device__ __forceinline__ unsigned short f2b(float f) {
  union { __hip_bfloat16 h; unsigned short u; } c;
  c.h = __float2bfloat16(f);
  return c.u;
}
__device__ __forceinline__ float b2f(unsigned short u) {
  union { unsigned int i; float f; } c;
  c.i = ((unsigned int)u) << 16;
  return c.f;
}

// ---------------------------------------------------------------------------
// Kernel 1: double-buffered (xS, aT) ping-pong on iteration parity:
//   stage xS[c] (|| stragglers' GEMM2(it-1) on buffers [c^1]) -> barrier A ->
//   GEMM1 (swapped, C[k][n]) -> 2-shfl softmax -> aT[c] -> barrier B ->
//   asum row-reduce + GEMM2 from xS[c]/aT[c].
// 2 barriers/iter (was 3); staging+HBM latency overlaps prior GEMM2.
// Epilogue: plain partial stores (no atomics).
// ---------------------------------------------------------------------------
__global__ __launch_bounds__(256) void nv_k1(
    const float* __restrict__ x, const float* __restrict__ conv_w,
    const float* __restrict__ conv_b, float* __restrict__ accP,
    float* __restrict__ asumP) {
  __shared__ __align__(16) short xS[2][NT * XSTR];  // xn tiles, bf16
  __shared__ __align__(16) short aT[2][Kc * NT];    // a^T tiles, swizzled

  const int tid = threadIdx.x;
  const int w = tid >> 6, l = tid & 63;
  const int bp = blockIdx.x;  // 0..1023
  const int b = bp / PB, p = bp % PB;
  const float* xb = x + (size_t)b * Nc * Dc + (size_t)p * RPB * Dc;

  // --- conv_w fragments (A-operand of swapped GEMM1), held in regs ---
  bf16x8 wf[4][4];
#pragma unroll
  for (int nt = 0; nt < 4; ++nt) {
    const int k = (l & 15) + 16 * nt;
#pragma unroll
    for (int ks = 0; ks < 4; ++ks) {
      const float* wp = conv_w + k * Dc + 8 * (l >> 4) + 32 * ks;
      const float4 w0 = *(const float4*)wp;
      const float4 w1 = *(const float4*)(wp + 4);
      union { unsigned int u[4]; bf16x8 v; } fu;
      fu.u[0] = pk(w0.x, w0.y); fu.u[1] = pk(w0.z, w0.w);
      fu.u[2] = pk(w1.x, w1.y); fu.u[3] = pk(w1.z, w1.w);
      wf[nt][ks] = fu.v;
    }
  }
  // bias per (nt,i): this lane's logit rows are k = 16nt + 4*(l>>4) + i
  float cb16[4][4];
#pragma unroll
  for (int nt = 0; nt < 4; ++nt)
#pragma unroll
    for (int i = 0; i < 4; ++i)
      cb16[nt][i] = conv_b[16 * nt + 4 * (l >> 4) + i];

  f32x16 acc2[2];
#pragma unroll
  for (int mt = 0; mt < 2; ++mt)
#pragma unroll
    for (int r = 0; r < 16; ++r) acc2[mt][r] = 0.f;
  float asum_acc = 0.f;  // partial for k = tid>>2 (4-lane groups)

  const int sr = tid >> 2, sq = tid & 3;
  float4 cur[8];
  {
    const float* gp = xb + (size_t)sr * Dc + 32 * sq;
#pragma unroll
    for (int j = 0; j < 8; ++j) cur[j] = *(const float4*)(gp + 4 * j);
  }

  const int dcol = (l & 31) + 32 * w;
  const int nmy = 16 * w + (l & 15);  // this lane's softmax column (row index)

  for (int it = 0; it < ITERS; ++it) {
    const int c = it & 1;
    short* xSc = &xS[c][0];
    short* aTc = &aT[c][0];

    // ---- normalize (4-lane shfl reduce) + cvt + stage into xS[c] ----
    // (no barrier needed: stragglers read buffers [c^1])
    float ss = 0.f;
#pragma unroll
    for (int j = 0; j < 8; ++j)
      ss += cur[j].x * cur[j].x + cur[j].y * cur[j].y +
            cur[j].z * cur[j].z + cur[j].w * cur[j].w;
    ss += __shfl_xor(ss, 1);
    ss += __shfl_xor(ss, 2);
    const float invn = 1.0f / fmaxf(sqrtf(ss), 1e-12f);
    {
      short* dst = xSc + sr * XSTR + 32 * sq;
#pragma unroll
      for (int j = 0; j < 4; ++j) {
        union { unsigned int u[4]; bf16x8 v; } fu;
        fu.u[0] = pk(cur[2 * j].x * invn, cur[2 * j].y * invn);
        fu.u[1] = pk(cur[2 * j].z * invn, cur[2 * j].w * invn);
        fu.u[2] = pk(cur[2 * j + 1].x * invn, cur[2 * j + 1].y * invn);
        fu.u[3] = pk(cur[2 * j + 1].z * invn, cur[2 * j + 1].w * invn);
        *(bf16x8*)(dst + 8 * j) = fu.v;
      }
    }
    // prefetch next tile (in flight across GEMM1+softmax+GEMM2)
    float4 nxt[8];
    if (it + 1 < ITERS) {
      const float* gp = xb + (size_t)((it + 1) * NT + sr) * Dc + 32 * sq;
#pragma unroll
      for (int j = 0; j < 8; ++j) nxt[j] = *(const float4*)(gp + 4 * j);
    }
    __syncthreads();  // barrier A: xS[c] ready

    // ---- GEMM1 (swapped): C[k][n]; lane holds k=16nt+4*(l>>4)+i, n=nmy ----
    f32x4 c1[4];
#pragma unroll
    for (int nt = 0; nt < 4; ++nt) {
      c1[nt][0] = 0.f; c1[nt][1] = 0.f; c1[nt][2] = 0.f; c1[nt][3] = 0.f;
    }
#pragma unroll
    for (int ks = 0; ks < 4; ++ks) {
      const bf16x8 af =
          *(const bf16x8*)(xSc + (16 * w + (l & 15)) * XSTR + 8 * (l >> 4) + 32 * ks);
#pragma unroll
      for (int nt = 0; nt < 4; ++nt)
        c1[nt] = __builtin_amdgcn_mfma_f32_16x16x32_bf16(wf[nt][ks], af,
                                                         c1[nt], 0, 0, 0);
    }

    // ---- softmax over k for column nmy: 16 in-lane + 2 shfl ----
    float e[4][4];
    float s = 0.f;
#pragma unroll
    for (int nt = 0; nt < 4; ++nt)
#pragma unroll
      for (int i = 0; i < 4; ++i) {
        e[nt][i] = __expf(c1[nt][i] + cb16[nt][i]);  // |logit|<=~2, no max
        s += e[nt][i];
      }
    s += __shfl_xor(s, 16);
    s += __shfl_xor(s, 32);
    const float inv = __builtin_amdgcn_rcpf(s);

    // ---- aT[c] writes (swizzled chunk layout, scalar b16 stores) ----
    {
      const int cn = nmy >> 2, nb = nmy & 3;
#pragma unroll
      for (int nt = 0; nt < 4; ++nt)
#pragma unroll
        for (int i = 0; i < 4; ++i) {
          const int k = 16 * nt + 4 * (l >> 4) + i;
          aTc[k * NT + ((cn ^ (k & 15)) << 2) + nb] = (short)f2b(e[nt][i] * inv);
        }
    }
    __syncthreads();  // barrier B: aT[c] ready

    // ---- asum partial from aT[c] (order-independent row sums) ----
    {
      const short* rp = aTc + (tid >> 2) * NT + (tid & 3) * 16;
      union { uint4 q; unsigned short h[8]; } q0, q1;
      q0.q = *(const uint4*)rp;
      q1.q = *(const uint4*)(rp + 8);
      float ps = 0.f;
#pragma unroll
      for (int j = 0; j < 8; ++j) ps += b2f(q0.h[j]) + b2f(q1.h[j]);
      ps += __shfl_xor(ps, 1);
      ps += __shfl_xor(ps, 2);
      asum_acc += ps;
    }

    // ---- GEMM2: acc[k][d] += a^T[k][n] * xn[n][d], 32x32x16 ----
#pragma unroll
    for (int ks2 = 0; ks2 < 4; ++ks2) {
      const int n0 = 16 * ks2 + 8 * (l >> 5);
      union { unsigned int u[4]; bf16x8 v; } bu;
#pragma unroll
      for (int j = 0; j < 4; ++j) {
        const unsigned short s0 =
            *(const unsigned short*)(xSc + (n0 + 2 * j) * XSTR + dcol);
        const unsigned short s1 =
            *(const unsigned short*)(xSc + (n0 + 2 * j + 1) * XSTR + dcol);
        bu.u[j] = (unsigned int)s0 | ((unsigned int)s1 << 16);
      }
#pragma unroll
      for (int mt = 0; mt < 2; ++mt) {
        const int k = (l & 31) + 32 * mt;
        const int cn = n0 >> 2;
        const uint2 lo = *(const uint2*)(aTc + k * NT + (((cn)     ^ (k & 15)) << 2));
        const uint2 hi = *(const uint2*)(aTc + k * NT + (((cn + 1) ^ (k & 15)) << 2));
        union { unsigned int u[4]; bf16x8 v; } au;
        au.u[0] = lo.x; au.u[1] = lo.y; au.u[2] = hi.x; au.u[3] = hi.y;
        acc2[mt] = __builtin_amdgcn_mfma_f32_32x32x16_bf16(au.v, bu.v,
                                                           acc2[mt], 0, 0, 0);
      }
    }
    if (it + 1 < ITERS) {
#pragma unroll
      for (int j = 0; j < 8; ++j) cur[j] = nxt[j];
    }
    // no trailing barrier: next staging writes buffer c^1
  }

  // ---- epilogue: plain partial stores (no atomics) ----
  if ((tid & 3) == 0) asumP[(size_t)bp * Kc + (tid >> 2)] = asum_acc;
  float* ap = accP + (size_t)bp * (Kc * Dc);
#pragma unroll
  for (int mt = 0; mt < 2; ++mt)
#pragma unroll
    for (int r = 0; r < 16; ++r) {
      const int k = 32 * mt + (r & 3) + 8 * (r >> 2) + 4 * (l >> 5);
      ap[k * Dc + dcol] = acc2[mt][r];
    }
}

// ---------------------------------------------------------------------------
// Kernel 2 (round-2 wide form): reduce 32 partials, subtract centroid*asum,
// intra-normalize over D, write out; per-(b,kg) sum-of-squares for k3.
// Grid: Bc*8 blocks; block (b,kg) handles clusters kg*8..kg*8+7.
// ---------------------------------------------------------------------------
__global__ __launch_bounds__(256) void nv_k2(
    const float* __restrict__ accP, const float* __restrict__ asumP,
    const float* __restrict__ cent, float* __restrict__ out,
    float* __restrict__ gssP) {
  __shared__ float asumS[8];
  __shared__ float redS[8][33];
  __shared__ float gssWv[4];
  const int tid = threadIdx.x;
  const int w = tid >> 6, l = tid & 63;
  const int b = blockIdx.x >> 3;
  const int kg = blockIdx.x & 7;

  {
    const int kk = tid >> 5, pp = tid & 31;  // 8 x 32
    redS[kk][pp] = asumP[(size_t)(b * PB + pp) * Kc + kg * 8 + kk];
  }
  __syncthreads();
  if (tid < 8) {
    float s = 0.f;
#pragma unroll
    for (int q = 0; q < 32; ++q) s += redS[tid][q];
    asumS[tid] = s;
  }
  __syncthreads();

  float gss = 0.f;
#pragma unroll
  for (int ki = 0; ki < 2; ++ki) {
    const int kloc = w + 4 * ki, k = kg * 8 + kloc;
    float v0 = 0.f, v1 = 0.f;
    for (int pp = 0; pp < PB; ++pp) {
      const float2 t = *(const float2*)(accP + (size_t)(b * PB + pp) * (Kc * Dc) +
                                        k * Dc + 2 * l);
      v0 += t.x;
      v1 += t.y;
    }
    const float as = asumS[kloc];
    const float2 c2 = *(const float2*)(cent + (size_t)k * Dc + 2 * l);
    v0 -= c2.x * as;
    v1 -= c2.y * as;
    float ssk = v0 * v0 + v1 * v1;
#pragma unroll
    for (int o = 1; o < 64; o <<= 1) ssk += __shfl_xor(ssk, o);
    const float sc = 1.0f / fmaxf(sqrtf(ssk), 1e-12f);
    gss += ssk * sc * sc;
    float2* o2 =
        reinterpret_cast<float2*>(out + (size_t)b * (Kc * Dc) + k * Dc + 2 * l);
    *o2 = make_float2(v0 * sc, v1 * sc);
  }
  if (l == 0) gssWv[w] = gss;
  __syncthreads();
  if (tid == 0) gssP[blockIdx.x] = gssWv[0] + gssWv[1] + gssWv[2] + gssWv[3];
}

// ---------------------------------------------------------------------------
// Kernel 3: global L2 normalization.
// ---------------------------------------------------------------------------
__global__ __launch_bounds__(256) void nv_k3(float* __restrict__ out,
                                             const float* __restrict__ gssP) {
  const int bid = blockIdx.x;
  const int b = bid >> 3;
  float g = 0.f;
#pragma unroll
  for (int i = 0; i < 8; ++i) g += gssP[b * 8 + i];
  const float gsc = 1.0f / fmaxf(sqrtf(g), 1e-12f);
  float4* o4 = reinterpret_cast<float4*>(out) + (size_t)bid * 256 + threadIdx.x;
  float4 v = *o4;
  v.x *= gsc;
  v.y *= gsc;
  v.z *= gsc;
  v.w *= gsc;
  *o4 = v;
}

}  // namespace

extern "C" void kernel_launch(void* const* d_in, const int* in_sizes, int n_in,
                              void* d_out, int out_size, void* d_ws,
                              size_t ws_size, hipStream_t stream) {
  const float* x = (const float*)d_in[0];
  const float* ce = (const float*)d_in[1];
  const float* cw = (const float*)d_in[2];
  const float* cb = (const float*)d_in[3];
  float* out = (float*)d_out;

  const size_t accPf = (size_t)Bc * PB * Kc * Dc;  // 8.39M floats (33.6 MB)
  const size_t asumPf = (size_t)Bc * PB * Kc;      // 65536 floats
  float* accP = (float*)d_ws;
  float* asumP = accP + accPf;
  float* gssP = asumP + asumPf;                    // Bc*8 floats

  nv_k1<<<Bc * PB, 256, 0, stream>>>(x, cw, cb, accP, asumP);
  nv_k2<<<Bc * 8, 256, 0, stream>>>(accP, asumP, ce, out, gssP);
  nv_k3<<<Bc * 8, 256, 0, stream>>>(out, gssP);
}